// Round 3
// baseline (75.551 us; speedup 1.0000x reference)
//
#include <hip/hip_runtime.h>
#include <math.h>

// LocalGroupedZernikeNewBP: fused grouped soft-abs + 3x3 box gain + tanh.
// Layout [B=8, H=256, W=256, C=36] fp32, channel-last.
// Groups: special 0..2 (plain tanh), low 3..5, mid 6..14, high 15..35.
//
// R3: owner-computes design. Thread t owns channel-quad j=t%9 (constant) of
// pixels p = t/9 + 28s. Loads coalesced; raw data stays in registers between
// sum phase and output phase; per-pixel group sums accumulate via ds_add_f32
// into a 10 KB LDS array; gains computed per interior pixel; stores coalesced.

static constexpr int IMG = 256;
static constexpr int NB = 8;
static constexpr int C = 36;
static constexpr int TS = 16;            // interior tile
static constexpr int HT = TS + 2;        // 18 (halo-inclusive)
static constexpr int NPIX = HT * HT;     // 324
static constexpr int ACT = 252;          // active stage threads (28 pixels x 9 quads)
static constexpr int PSTEP = 28;         // pixels per sweep
static constexpr int NSWEEP = 12;        // ceil(324/28)

__global__ __launch_bounds__(256) void lgz_kernel(
    const float* __restrict__ in, float* __restrict__ out,
    const float* __restrict__ p_sp_bias, const float* __restrict__ p_sp_alpha,
    const float* __restrict__ p_sp_amax,
    const float* __restrict__ p_lo_bias, const float* __restrict__ p_lo_alpha,
    const float* __restrict__ p_lo_amax, const float* __restrict__ p_lo_eps,
    const float* __restrict__ p_lo_gss, const float* __restrict__ p_lo_psat,
    const float* __restrict__ p_mi_bias, const float* __restrict__ p_mi_alpha,
    const float* __restrict__ p_mi_amax, const float* __restrict__ p_mi_eps,
    const float* __restrict__ p_mi_gss, const float* __restrict__ p_mi_psat,
    const float* __restrict__ p_hi_bias, const float* __restrict__ p_hi_alpha,
    const float* __restrict__ p_hi_amax, const float* __restrict__ p_hi_eps,
    const float* __restrict__ p_hi_gss, const float* __restrict__ p_hi_psat)
{
    __shared__ float4 s_sum4[NPIX];    // per pixel (lo,mi,hi,trash) accum
    __shared__ float4 s_gain4[NPIX];   // per pixel (Glo,Gmi,Ghi,-), interior only
    float* ss = reinterpret_cast<float*>(s_sum4);

    const int tid = threadIdx.x;
    const int bx0 = blockIdx.x * TS, by0 = blockIdx.y * TS;
    const float* img = in + (size_t)blockIdx.z * IMG * IMG * C;
    float* oimg = out + (size_t)blockIdx.z * IMG * IMG * C;

    const float b_sp = p_sp_bias[0], a_sp = p_sp_alpha[0], m_sp = p_sp_amax[0];
    const float b_lo = p_lo_bias[0], a_lo = p_lo_alpha[0], m_lo = p_lo_amax[0];
    const float e_lo = p_lo_eps[0],  g_lo = p_lo_gss[0],  q_lo = p_lo_psat[0];
    const float b_mi = p_mi_bias[0], a_mi = p_mi_alpha[0], m_mi = p_mi_amax[0];
    const float e_mi = p_mi_eps[0],  g_mi = p_mi_gss[0],  q_mi = p_mi_psat[0];
    const float b_hi = p_hi_bias[0], a_hi = p_hi_alpha[0], m_hi = p_hi_amax[0];
    const float e_hi = p_hi_eps[0],  g_hi = p_hi_gss[0],  q_hi = p_hi_psat[0];

    // folded gain numerators (x2 for tanh via exp(2v)) and 1/p_sat
    const float Clo = 2.0f * a_lo * g_lo, inv_qlo = __fdividef(1.0f, q_lo);
    const float Cmi = 2.0f * a_mi * g_mi, inv_qmi = __fdividef(1.0f, q_mi);
    const float Chi = 2.0f * a_hi * g_hi, inv_qhi = __fdividef(1.0f, q_hi);
    const float G_sp = 2.0f * a_sp;

    // zero the sum accumulators
    const float4 z4 = make_float4(0.f, 0.f, 0.f, 0.f);
    for (int i = tid; i < NPIX; i += 256) s_sum4[i] = z4;

    // ---- per-thread constants from fixed channel-quad j ----
    const bool active = tid < ACT;
    const int j = tid % 9;
    const int p0 = tid / 9;
    const int c0 = 4 * j;
    float biasK[4], epsK[4], amaxK[4], amax2K[4];
    #pragma unroll
    for (int k = 0; k < 4; ++k) {
        const int c = c0 + k;
        biasK[k]  = c < 3 ? b_sp : (c < 6 ? b_lo : (c < 15 ? b_mi : b_hi));
        epsK[k]   = c < 6 ? e_lo : (c < 15 ? e_mi : e_hi);   // c<3 contributes nothing
        const float mm = c < 3 ? m_sp : (c < 6 ? m_lo : (c < 15 ? m_mi : m_hi));
        amaxK[k] = mm; amax2K[k] = 2.0f * mm;
    }
    // group codes: 0=lo 1=mi 2=hi 3=special(no sum)
    #define GRP(c) ((c) < 3 ? 3 : ((c) < 6 ? 0 : ((c) < 15 ? 1 : 2)))
    const int gA = GRP(c0), gB = GRP(c0 + 3);
    const int ks = 1 + (GRP(c0 + 1) == gA) + (GRP(c0 + 2) == gA) + (GRP(c0 + 3) == gA);
    #undef GRP

    // ---- phase 1a: issue all loads (coalesced: F4 = tid + 252*s) ----
    float4 x[NSWEEP];
    int voff[NSWEEP];
    unsigned pmask = 0;
    {
        int p = p0;
        #pragma unroll
        for (int s = 0; s < NSWEEP; ++s, p += PSTEP) {
            const bool val = active && p < NPIX;
            const int r = p / HT, px = p - r * HT;
            const int gy = min(max(by0 + r - 1, 0), IMG - 1);
            const int gx = min(max(bx0 + px - 1, 0), IMG - 1);
            const int vo = ((gy << 8) + gx) * (C * 4) + j * 16;
            voff[s] = vo;
            const bool inter = (unsigned)(r - 1) < (unsigned)TS &&
                               (unsigned)(px - 1) < (unsigned)TS;
            if (val && inter) pmask |= (1u << s);
            x[s] = val ? *reinterpret_cast<const float4*>(
                             reinterpret_cast<const char*>(img) + vo)
                       : z4;
        }
    }
    __syncthreads();   // zero-fill visible before any ds_add

    // ---- phase 1b: soft-abs partial sums -> ds_add ----
    {
        int p = p0;
        #pragma unroll
        for (int s = 0; s < NSWEEP; ++s, p += PSTEP) {
            const bool val = active && p < NPIX;
            if (val) {
                const float xs[4] = {x[s].x, x[s].y, x[s].z, x[s].w};
                float t[4];
                #pragma unroll
                for (int k = 0; k < 4; ++k) {
                    const float u = xs[k] + biasK[k];
                    t[k] = sqrtf(fmaf(u, u, epsK[k]));
                }
                const float tot = (t[0] + t[1]) + (t[2] + t[3]);
                float segA = t[0];
                if (ks > 1) segA += t[1];
                if (ks > 2) segA += t[2];
                if (ks > 3) segA += t[3];
                const float segB = tot - segA;
                if (gA != 3) atomicAdd(&ss[p * 4 + gA], segA);
                if (ks < 4) atomicAdd(&ss[p * 4 + gB], segB);
            }
        }
    }
    __syncthreads();

    // ---- phase 2: 3x3 box sum + gains for the 256 interior pixels ----
    {
        const int r = (tid >> 4) + 1, px = (tid & 15) + 1;
        float slo = 0.f, smi = 0.f, shi = 0.f;
        #pragma unroll
        for (int dr = -1; dr <= 1; ++dr) {
            #pragma unroll
            for (int dc = -1; dc <= 1; ++dc) {
                const float4 v = s_sum4[(r + dr) * HT + (px + dc)];
                slo += v.x; smi += v.y; shi += v.z;
            }
        }
        const float Gl = __fdividef(Clo, fmaf(slo, inv_qlo, 1.0f));
        const float Gm = __fdividef(Cmi, fmaf(smi, inv_qmi, 1.0f));
        const float Gh = __fdividef(Chi, fmaf(shi, inv_qhi, 1.0f));
        s_gain4[r * HT + px] = make_float4(Gl, Gm, Gh, 0.f);
    }
    __syncthreads();

    // ---- phase 3: outputs from registers, coalesced stores ----
    {
        int p = p0;
        #pragma unroll
        for (int s = 0; s < NSWEEP; ++s, p += PSTEP) {
            if ((pmask >> s) & 1u) {
                const float4 g = s_gain4[p];
                const float GA = gA == 0 ? g.x : (gA == 1 ? g.y : (gA == 2 ? g.z : G_sp));
                const float GB = gB == 0 ? g.x : (gB == 1 ? g.y : g.z);
                const float xs[4] = {x[s].x, x[s].y, x[s].z, x[s].w};
                float o[4];
                #pragma unroll
                for (int k = 0; k < 4; ++k) {
                    const float G = (k < ks) ? GA : GB;
                    const float u = xs[k] + biasK[k];
                    const float e = __expf(G * u);
                    o[k] = amaxK[k] - __fdividef(amax2K[k], e + 1.0f);
                }
                *reinterpret_cast<float4*>(reinterpret_cast<char*>(oimg) + voff[s]) =
                    make_float4(o[0], o[1], o[2], o[3]);
            }
        }
    }
}

extern "C" void kernel_launch(void* const* d_in, const int* in_sizes, int n_in,
                              void* d_out, int out_size, void* d_ws, size_t ws_size,
                              hipStream_t stream) {
    const float* raw = (const float*)d_in[0];
    dim3 grid(IMG / TS, IMG / TS, NB);
    dim3 block(256);
    lgz_kernel<<<grid, block, 0, stream>>>(
        raw, (float*)d_out,
        (const float*)d_in[1], (const float*)d_in[2], (const float*)d_in[3],
        (const float*)d_in[5], (const float*)d_in[6], (const float*)d_in[7],
        (const float*)d_in[8], (const float*)d_in[9], (const float*)d_in[10],
        (const float*)d_in[11], (const float*)d_in[12], (const float*)d_in[13],
        (const float*)d_in[14], (const float*)d_in[15], (const float*)d_in[16],
        (const float*)d_in[17], (const float*)d_in[18], (const float*)d_in[19],
        (const float*)d_in[20], (const float*)d_in[21], (const float*)d_in[22]);
}

// Round 5
// 58.191 us; speedup vs baseline: 1.2983x; 1.2983x over previous
//
#include <hip/hip_runtime.h>
#include <math.h>

// LocalGroupedZernikeNewBP: fused grouped soft-abs + 3x3 box gain + tanh.
// Layout [B=8, H=256, W=256, C=36] fp32, channel-last.
// Groups: special 0..2 (plain tanh), low 3..5, mid 6..14, high 15..35.
//
// R5 = R4 with the lane-63 clobber fixed (store requires act && j==0).
//  K1: per-pixel group sums. Wave lanes 0..62 own 63 consecutive float4 =
//      7 pixels x 9 quads. Segmented shfl_down reduction (seg = lane%9),
//      head lanes store float4(lo,mi,hi,0) to d_ws. No LDS/barriers/atomics.
//  K2: thread-per-pixel. 3x3 box sum from d_ws (L1/L2-hot), gains, re-read
//      own raw channels (LLC-hot), tanh, coalesced float4 stores.

static constexpr int IMG = 256;
static constexpr int NB = 8;
static constexpr int NPIX = NB * IMG * IMG;   // 524288

__global__ __launch_bounds__(256) void k1_sums(
    const float4* __restrict__ in4, float4* __restrict__ sums,
    const float* __restrict__ pb_lo, const float* __restrict__ pe_lo,
    const float* __restrict__ pb_mi, const float* __restrict__ pe_mi,
    const float* __restrict__ pb_hi, const float* __restrict__ pe_hi)
{
    const float b_lo = pb_lo[0], e_lo = pe_lo[0];
    const float b_mi = pb_mi[0], e_mi = pe_mi[0];
    const float b_hi = pb_hi[0], e_hi = pe_hi[0];

    const int lane = threadIdx.x & 63;
    const int j = lane % 9;                 // quad within pixel
    const bool act = lane < 63;             // lane 63 idle (63 = 7 pix x 9 quads)
    const int sub = lane / 9;               // pixel offset within wave's 7
    const int c0 = 4 * j;

    float biasK[4], epsK[4], mLo[4], mMi[4], mHi[4];
    #pragma unroll
    for (int k = 0; k < 4; ++k) {
        const int c = c0 + k;
        biasK[k] = c < 3 ? 0.f : (c < 6 ? b_lo : (c < 15 ? b_mi : b_hi));
        epsK[k]  = c < 6 ? e_lo : (c < 15 ? e_mi : e_hi);
        mLo[k] = (c >= 3 && c < 6) ? 1.f : 0.f;
        mMi[k] = (c >= 6 && c < 15) ? 1.f : 0.f;
        mHi[k] = (c >= 15) ? 1.f : 0.f;
    }

    const int wid = blockIdx.x * (blockDim.x >> 6) + (threadIdx.x >> 6);
    const int nw  = gridDim.x * (blockDim.x >> 6);

    for (int pix0 = wid * 7; pix0 < NPIX; pix0 += nw * 7) {
        const int myPix = pix0 + sub;
        float4 x = make_float4(0.f, 0.f, 0.f, 0.f);
        if (act && myPix < NPIX) x = in4[pix0 * 9 + lane];

        const float xs[4] = {x.x, x.y, x.z, x.w};
        float t[4];
        #pragma unroll
        for (int k = 0; k < 4; ++k) {
            const float u = xs[k] + biasK[k];
            t[k] = sqrtf(fmaf(u, u, epsK[k]));
        }
        float pl = 0.f, pm = 0.f, ph = 0.f;
        #pragma unroll
        for (int k = 0; k < 4; ++k) {
            pl = fmaf(mLo[k], t[k], pl);
            pm = fmaf(mMi[k], t[k], pm);
            ph = fmaf(mHi[k], t[k], ph);
        }
        // segmented reduction: after d=1,2,4,8 lane j covers [j, min(j+2d-1,8)]
        #pragma unroll
        for (int d = 1; d < 16; d <<= 1) {
            const float al = __shfl_down(pl, d);
            const float am = __shfl_down(pm, d);
            const float ah = __shfl_down(ph, d);
            if (j + d < 9) { pl += al; pm += am; ph += ah; }
        }
        if (act && j == 0 && myPix < NPIX)     // act: lane 63 must NOT store
            sums[myPix] = make_float4(pl, pm, ph, 0.f);
    }
}

__global__ __launch_bounds__(256) void k2_out(
    const float4* __restrict__ in4, const float4* __restrict__ sums,
    float4* __restrict__ out4,
    const float* __restrict__ p_sp_bias, const float* __restrict__ p_sp_alpha,
    const float* __restrict__ p_sp_amax,
    const float* __restrict__ p_lo_bias, const float* __restrict__ p_lo_alpha,
    const float* __restrict__ p_lo_amax, const float* __restrict__ p_lo_gss,
    const float* __restrict__ p_lo_psat,
    const float* __restrict__ p_mi_bias, const float* __restrict__ p_mi_alpha,
    const float* __restrict__ p_mi_amax, const float* __restrict__ p_mi_gss,
    const float* __restrict__ p_mi_psat,
    const float* __restrict__ p_hi_bias, const float* __restrict__ p_hi_alpha,
    const float* __restrict__ p_hi_amax, const float* __restrict__ p_hi_gss,
    const float* __restrict__ p_hi_psat)
{
    const int p = blockIdx.x * 256 + threadIdx.x;   // exact: 2048*256 = NPIX

    const float b_sp = p_sp_bias[0], a_sp = p_sp_alpha[0], m_sp = p_sp_amax[0];
    const float b_lo = p_lo_bias[0], a_lo = p_lo_alpha[0], m_lo = p_lo_amax[0];
    const float g_lo = p_lo_gss[0],  q_lo = p_lo_psat[0];
    const float b_mi = p_mi_bias[0], a_mi = p_mi_alpha[0], m_mi = p_mi_amax[0];
    const float g_mi = p_mi_gss[0],  q_mi = p_mi_psat[0];
    const float b_hi = p_hi_bias[0], a_hi = p_hi_alpha[0], m_hi = p_hi_amax[0];
    const float g_hi = p_hi_gss[0],  q_hi = p_hi_psat[0];

    const float Clo = 2.0f * a_lo * g_lo, inv_qlo = __fdividef(1.0f, q_lo);
    const float Cmi = 2.0f * a_mi * g_mi, inv_qmi = __fdividef(1.0f, q_mi);
    const float Chi = 2.0f * a_hi * g_hi, inv_qhi = __fdividef(1.0f, q_hi);
    const float G_sp = 2.0f * a_sp;

    const int x = p & 255, y = (p >> 8) & 255;
    const int rowb = p - x;                                // b*65536 + y*256
    const int xm = max(x - 1, 0), xp = min(x + 1, 255);
    const int rm = rowb - (y > 0 ? 256 : 0);
    const int rp = rowb + (y < 255 ? 256 : 0);

    float slo = 0.f, smi = 0.f, shi = 0.f;
    const int rows[3] = {rm, rowb, rp};
    #pragma unroll
    for (int i = 0; i < 3; ++i) {
        const float4 a = sums[rows[i] + xm];
        const float4 b = sums[rows[i] + x];
        const float4 c = sums[rows[i] + xp];
        slo += a.x + b.x + c.x;
        smi += a.y + b.y + c.y;
        shi += a.z + b.z + c.z;
    }
    const float Gl = __fdividef(Clo, fmaf(slo, inv_qlo, 1.0f));
    const float Gm = __fdividef(Cmi, fmaf(smi, inv_qmi, 1.0f));
    const float Gh = __fdividef(Chi, fmaf(shi, inv_qhi, 1.0f));

    float v[36];
    {
        const float4* src = in4 + p * 9;
        #pragma unroll
        for (int q = 0; q < 9; ++q) reinterpret_cast<float4*>(v)[q] = src[q];
    }
    // out = m*tanh(a*u) = m - 2m/(exp(2*a*u)+1); G holds the 2*alpha*gain factor
    #pragma unroll
    for (int c = 0; c < 3; ++c) {
        const float e = __expf(G_sp * (v[c] + b_sp));
        v[c] = m_sp - __fdividef(2.0f * m_sp, e + 1.0f);
    }
    #pragma unroll
    for (int c = 3; c < 6; ++c) {
        const float e = __expf(Gl * (v[c] + b_lo));
        v[c] = m_lo - __fdividef(2.0f * m_lo, e + 1.0f);
    }
    #pragma unroll
    for (int c = 6; c < 15; ++c) {
        const float e = __expf(Gm * (v[c] + b_mi));
        v[c] = m_mi - __fdividef(2.0f * m_mi, e + 1.0f);
    }
    #pragma unroll
    for (int c = 15; c < 36; ++c) {
        const float e = __expf(Gh * (v[c] + b_hi));
        v[c] = m_hi - __fdividef(2.0f * m_hi, e + 1.0f);
    }

    float4* dst = out4 + p * 9;
    #pragma unroll
    for (int q = 0; q < 9; ++q) dst[q] = reinterpret_cast<const float4*>(v)[q];
}

extern "C" void kernel_launch(void* const* d_in, const int* in_sizes, int n_in,
                              void* d_out, int out_size, void* d_ws, size_t ws_size,
                              hipStream_t stream) {
    const float4* in4 = (const float4*)d_in[0];
    float4* sums = (float4*)d_ws;     // NPIX * 16 B = 8.4 MB scratch
    float4* out4 = (float4*)d_out;

    k1_sums<<<2048, 256, 0, stream>>>(
        in4, sums,
        (const float*)d_in[5], (const float*)d_in[8],     // low bias, eps
        (const float*)d_in[11], (const float*)d_in[14],   // mid bias, eps
        (const float*)d_in[17], (const float*)d_in[20]);  // high bias, eps

    k2_out<<<NPIX / 256, 256, 0, stream>>>(
        in4, sums, out4,
        (const float*)d_in[1], (const float*)d_in[2], (const float*)d_in[3],
        (const float*)d_in[5], (const float*)d_in[6], (const float*)d_in[7],
        (const float*)d_in[9], (const float*)d_in[10],
        (const float*)d_in[11], (const float*)d_in[12], (const float*)d_in[13],
        (const float*)d_in[15], (const float*)d_in[16],
        (const float*)d_in[17], (const float*)d_in[18], (const float*)d_in[19],
        (const float*)d_in[21], (const float*)d_in[22]);
}

// Round 6
// 52.898 us; speedup vs baseline: 1.4282x; 1.1001x over previous
//
#include <hip/hip_runtime.h>
#include <math.h>

// LocalGroupedZernikeNewBP: fused grouped soft-abs + 3x3 box gain + tanh.
// Layout [B=8, H=256, W=256, C=36] fp32, channel-last.
// Groups: special 0..2 (plain tanh), low 3..5, mid 6..14, high 15..35.
//
// R6: three barrier-free streaming kernels, every global access float4-linear.
//  K1 : per-pixel group sums (segmented shfl over lane%9). -> sums (d_out scratch)
//  K15: thread-per-pixel 3x3 box sum of sums -> folded gains (Glo,Gmi,Ghi,Gsp)
//  K2 : thread-per-float4; coalesced in/out, gains broadcast via L1.
//       d_out scratch region is fully overwritten by K2 (sums dead by then).

static constexpr int IMG = 256;
static constexpr int NB = 8;
static constexpr int NPIX = NB * IMG * IMG;   // 524288
static constexpr int NF4 = NPIX * 9;          // 4718592 float4 in tensor

__global__ __launch_bounds__(256) void k1_sums(
    const float4* __restrict__ in4, float4* __restrict__ sums,
    const float* __restrict__ pb_lo, const float* __restrict__ pe_lo,
    const float* __restrict__ pb_mi, const float* __restrict__ pe_mi,
    const float* __restrict__ pb_hi, const float* __restrict__ pe_hi)
{
    const float b_lo = pb_lo[0], e_lo = pe_lo[0];
    const float b_mi = pb_mi[0], e_mi = pe_mi[0];
    const float b_hi = pb_hi[0], e_hi = pe_hi[0];

    const int lane = threadIdx.x & 63;
    const int j = lane % 9;                 // quad within pixel
    const bool act = lane < 63;             // lane 63 idle (63 = 7 pix x 9 quads)
    const int sub = lane / 9;               // pixel offset within wave's 7
    const int c0 = 4 * j;

    float biasK[4], epsK[4], mLo[4], mMi[4], mHi[4];
    #pragma unroll
    for (int k = 0; k < 4; ++k) {
        const int c = c0 + k;
        biasK[k] = c < 3 ? 0.f : (c < 6 ? b_lo : (c < 15 ? b_mi : b_hi));
        epsK[k]  = c < 6 ? e_lo : (c < 15 ? e_mi : e_hi);
        mLo[k] = (c >= 3 && c < 6) ? 1.f : 0.f;
        mMi[k] = (c >= 6 && c < 15) ? 1.f : 0.f;
        mHi[k] = (c >= 15) ? 1.f : 0.f;
    }

    const int wid = blockIdx.x * (blockDim.x >> 6) + (threadIdx.x >> 6);
    const int nw  = gridDim.x * (blockDim.x >> 6);

    for (int pix0 = wid * 7; pix0 < NPIX; pix0 += nw * 7) {
        const int myPix = pix0 + sub;
        float4 x = make_float4(0.f, 0.f, 0.f, 0.f);
        if (act && myPix < NPIX) x = in4[pix0 * 9 + lane];

        const float xs[4] = {x.x, x.y, x.z, x.w};
        float t[4];
        #pragma unroll
        for (int k = 0; k < 4; ++k) {
            const float u = xs[k] + biasK[k];
            t[k] = sqrtf(fmaf(u, u, epsK[k]));
        }
        float pl = 0.f, pm = 0.f, ph = 0.f;
        #pragma unroll
        for (int k = 0; k < 4; ++k) {
            pl = fmaf(mLo[k], t[k], pl);
            pm = fmaf(mMi[k], t[k], pm);
            ph = fmaf(mHi[k], t[k], ph);
        }
        // segmented reduction: after d=1,2,4,8 lane j covers [j, min(j+2d-1,8)]
        #pragma unroll
        for (int d = 1; d < 16; d <<= 1) {
            const float al = __shfl_down(pl, d);
            const float am = __shfl_down(pm, d);
            const float ah = __shfl_down(ph, d);
            if (j + d < 9) { pl += al; pm += am; ph += ah; }
        }
        if (act && j == 0 && myPix < NPIX)     // lane 63 must NOT store
            sums[myPix] = make_float4(pl, pm, ph, 0.f);
    }
}

__global__ __launch_bounds__(256) void k15_gains(
    const float4* __restrict__ sums, float4* __restrict__ gains,
    const float* __restrict__ p_sp_alpha,
    const float* __restrict__ p_lo_alpha, const float* __restrict__ p_lo_gss,
    const float* __restrict__ p_lo_psat,
    const float* __restrict__ p_mi_alpha, const float* __restrict__ p_mi_gss,
    const float* __restrict__ p_mi_psat,
    const float* __restrict__ p_hi_alpha, const float* __restrict__ p_hi_gss,
    const float* __restrict__ p_hi_psat)
{
    const int p = blockIdx.x * 256 + threadIdx.x;   // exact: 2048*256 = NPIX

    const float Clo = 2.0f * p_lo_alpha[0] * p_lo_gss[0];
    const float Cmi = 2.0f * p_mi_alpha[0] * p_mi_gss[0];
    const float Chi = 2.0f * p_hi_alpha[0] * p_hi_gss[0];
    const float inv_qlo = __fdividef(1.0f, p_lo_psat[0]);
    const float inv_qmi = __fdividef(1.0f, p_mi_psat[0]);
    const float inv_qhi = __fdividef(1.0f, p_hi_psat[0]);
    const float G_sp = 2.0f * p_sp_alpha[0];

    const int x = p & 255, y = (p >> 8) & 255;
    const int rowb = p - x;                                // b*65536 + y*256
    const int xm = max(x - 1, 0), xp = min(x + 1, 255);
    const int rm = rowb - (y > 0 ? 256 : 0);
    const int rp = rowb + (y < 255 ? 256 : 0);

    float slo = 0.f, smi = 0.f, shi = 0.f;
    const int rows[3] = {rm, rowb, rp};
    #pragma unroll
    for (int i = 0; i < 3; ++i) {
        const float4 a = sums[rows[i] + xm];
        const float4 b = sums[rows[i] + x];
        const float4 c = sums[rows[i] + xp];
        slo += a.x + b.x + c.x;
        smi += a.y + b.y + c.y;
        shi += a.z + b.z + c.z;
    }
    const float Gl = __fdividef(Clo, fmaf(slo, inv_qlo, 1.0f));
    const float Gm = __fdividef(Cmi, fmaf(smi, inv_qmi, 1.0f));
    const float Gh = __fdividef(Chi, fmaf(shi, inv_qhi, 1.0f));
    gains[p] = make_float4(Gl, Gm, Gh, G_sp);
}

__global__ __launch_bounds__(256) void k2_out(
    const float4* __restrict__ in4, const float4* __restrict__ gains,
    float4* __restrict__ out4,
    const float* __restrict__ pb_sp, const float* __restrict__ pm_sp,
    const float* __restrict__ pb_lo, const float* __restrict__ pm_lo,
    const float* __restrict__ pb_mi, const float* __restrict__ pm_mi,
    const float* __restrict__ pb_hi, const float* __restrict__ pm_hi)
{
    const int F = blockIdx.x * 256 + threadIdx.x;   // exact: 18432*256 = NF4
    const int p = F / 9;                            // magic-mul division
    const int j = F - 9 * p;
    const int c0 = 4 * j;

    const float b_sp = pb_sp[0], m_sp = pm_sp[0];
    const float b_lo = pb_lo[0], m_lo = pm_lo[0];
    const float b_mi = pb_mi[0], m_mi = pm_mi[0];
    const float b_hi = pb_hi[0], m_hi = pm_hi[0];

    const float4 g = gains[p];
    const float4 x = in4[F];
    const float xs[4] = {x.x, x.y, x.z, x.w};
    float o[4];
    #pragma unroll
    for (int k = 0; k < 4; ++k) {
        const int c = c0 + k;
        const float G    = c < 3 ? g.w  : (c < 6 ? g.x  : (c < 15 ? g.y  : g.z));
        const float bias = c < 3 ? b_sp : (c < 6 ? b_lo : (c < 15 ? b_mi : b_hi));
        const float m    = c < 3 ? m_sp : (c < 6 ? m_lo : (c < 15 ? m_mi : m_hi));
        // m*tanh(v) = m - 2m/(exp(2v)+1); G already carries the factor 2
        const float e = __expf(G * (xs[k] + bias));
        o[k] = m - __fdividef(2.0f * m, e + 1.0f);
    }
    out4[F] = make_float4(o[0], o[1], o[2], o[3]);
}

extern "C" void kernel_launch(void* const* d_in, const int* in_sizes, int n_in,
                              void* d_out, int out_size, void* d_ws, size_t ws_size,
                              hipStream_t stream) {
    const float4* in4 = (const float4*)d_in[0];
    float4* out4  = (float4*)d_out;
    float4* sums  = (float4*)d_out;   // scratch: first 8.4 MB of d_out, dead
                                      // before K2 fully overwrites d_out
    float4* gains = (float4*)d_ws;    // 8.4 MB

    k1_sums<<<2048, 256, 0, stream>>>(
        in4, sums,
        (const float*)d_in[5], (const float*)d_in[8],     // low bias, eps
        (const float*)d_in[11], (const float*)d_in[14],   // mid bias, eps
        (const float*)d_in[17], (const float*)d_in[20]);  // high bias, eps

    k15_gains<<<NPIX / 256, 256, 0, stream>>>(
        sums, gains,
        (const float*)d_in[2],                            // special alpha
        (const float*)d_in[6], (const float*)d_in[9], (const float*)d_in[10],
        (const float*)d_in[12], (const float*)d_in[15], (const float*)d_in[16],
        (const float*)d_in[18], (const float*)d_in[21], (const float*)d_in[22]);

    k2_out<<<NF4 / 256, 256, 0, stream>>>(
        in4, gains, out4,
        (const float*)d_in[1], (const float*)d_in[3],     // special bias, amax
        (const float*)d_in[5], (const float*)d_in[7],     // low bias, amax
        (const float*)d_in[11], (const float*)d_in[13],   // mid bias, amax
        (const float*)d_in[17], (const float*)d_in[19]);  // high bias, amax
}